// Round 3
// baseline (1184.858 us; speedup 1.0000x reference)
//
#include <hip/hip_runtime.h>
#include <hip/hip_bf16.h>

#define EPSV 1e-12
#define RHASH 0.2

__device__ __forceinline__ int fmod2(double t) {
    // floor then mod 2 with numpy semantics (non-negative result)
    return (int)(((long long)floor(t)) & 1LL);
}

// ---------------------------------------------------------------------------
// setup: per-layer kernel hashes kh[], per-cin a-sums, query constants (double)
// dmeta layout: [0..2]=asum1, [3..18]=asum2, [19..38]=asum3, [39]=qc1,[40]=qc2,[41]=qc3
// imeta layout: [0..15]=kh1, [16..35]=kh2, [36..55]=kh3
// (identical to the verified round-2 version)
// ---------------------------------------------------------------------------
__device__ void layer_setup(const float* W, const float* a, double cval,
                            int Co, int Ci, int* kh, double* asum, double* qc,
                            double* s_norm, float* Wbuf, float* abuf)
{
    const int t = threadIdx.x;
    const int D = Ci * 25;
    for (int i = t; i < Co * D; i += 256) Wbuf[i] = W[i];
    for (int i = t; i < D + 5; i += 256) abuf[i] = a[i];
    __syncthreads();
    if (t < Co) {
        double s = 0;
        for (int j = 0; j < D; ++j) { double w = (double)Wbuf[t * D + j]; s += w * w; }
        s_norm[t] = sqrt(s);
    }
    __syncthreads();
    if (t == 0) {
        double mx = 0;
        for (int i = 0; i < Co; ++i) mx = fmax(mx, s_norm[i]);
        s_norm[23] = 1.0 / (mx + EPSV);
    }
    __syncthreads();
    double scale = s_norm[23];
    if (t < Co) {
        double dp = 0;
        for (int j = 0; j < D; ++j) dp += (double)Wbuf[t * D + j] * (double)abuf[j];
        dp *= scale;
        double n = s_norm[t] * scale;
        double p = n * n;                       // n^2, n^4, n^8, n^16, n^32
        for (int m = 0; m < 5; ++m) { dp += p * (double)abuf[D + m]; p *= p; }
        kh[t] = fmod2((dp + cval) / RHASH);
    }
    if (t >= 64 && t < 64 + Ci) {
        int c = t - 64;
        double s = 0;
        for (int j = 0; j < 25; ++j) s += (double)abuf[c * 25 + j];
        asum[c] = s;
    }
    if (t == 128) {
        double s = 0;
        for (int m = 0; m < 5; ++m) s += (double)abuf[D + m];
        *qc = 0.5 * s + cval;
    }
    __syncthreads();
}

__global__ __launch_bounds__(256) void setup_kernel(
    const float* W1, const float* a1, const float* c1,
    const float* W2, const float* a2, const float* c2,
    const float* W3, const float* a3, const float* c3,
    double* dmeta, int* imeta)
{
    __shared__ float Wbuf[10000];
    __shared__ float abuf[512];
    __shared__ double s_norm[24];
    layer_setup(W1, a1, (double)c1[0], 16, 3,  imeta + 0,  dmeta + 0,  dmeta + 39, s_norm, Wbuf, abuf);
    layer_setup(W2, a2, (double)c2[0], 20, 16, imeta + 16, dmeta + 3,  dmeta + 40, s_norm, Wbuf, abuf);
    layer_setup(W3, a3, (double)c3[0], 20, 20, imeta + 36, dmeta + 19, dmeta + 41, s_norm, Wbuf, abuf);
}

// ---------------------------------------------------------------------------
// conv1: x[B,3,32,32] f32 -> h1[B,16,16,16] f32 (conv+bias+relu+mask+pool)
// one block per sample; thread = one pre-pool position (4 serial passes of 256);
// all 16 co in registers; weights via block-uniform (scalar) global loads;
// pooling via shfl_xor; channel sums via wave butterflies.
// ---------------------------------------------------------------------------
__global__ __launch_bounds__(256) void conv1_kernel(
    const float* __restrict__ x, const float* __restrict__ W1,
    const float* __restrict__ b1, const int* __restrict__ kh1,
    const double* __restrict__ dmeta, float* __restrict__ h1)
{
    __shared__ float xs[3][36][36];
    __shared__ double s_csum[3];

    const int b = blockIdx.x, t = threadIdx.x;

    for (int i = t; i < 3 * 36 * 36; i += 256) (&xs[0][0][0])[i] = 0.f;
    __syncthreads();
    const float2* xb2 = (const float2*)(x + (size_t)b * 3072);
    for (int i = t; i < 1536; i += 256) {
        int idx = i * 2;
        int c = idx >> 10, rem = idx & 1023;
        *(float2*)&xs[c][(rem >> 5) + 2][(rem & 31) + 2] = xb2[i];
    }
    __syncthreads();
    {   // channel sums: wave w (w<3) reduces channel w
        int w = t >> 6, ln = t & 63;
        if (w < 3) {
            double s = 0;
            for (int j = 0; j < 16; ++j) {
                int i = ln + 64 * j;
                s += (double)xs[w][(i >> 5) + 2][(i & 31) + 2];
            }
            #pragma unroll
            for (int off = 32; off; off >>= 1) s += __shfl_xor(s, off);
            if (ln == 0) s_csum[w] = s;
        }
    }
    __syncthreads();
    // per-thread hash (redundant but cheap; avoids extra sync)
    double dp = 0, nn = 0;
    #pragma unroll
    for (int c = 0; c < 3; ++c) {
        double cm = s_csum[c] * (1.0 / 1024.0);
        dp += cm * dmeta[c]; nn += cm * cm;
    }
    const int qh = fmod2((dp / (5.0 * sqrt(nn) + EPSV) + dmeta[39]) / RHASH);

    for (int p = 0; p < 4; ++p) {
        const int pos = p * 256 + t;
        const int yy = pos >> 5, xx = pos & 31;
        float acc[16];
        #pragma unroll
        for (int c = 0; c < 16; ++c) acc[c] = b1[c];
        #pragma unroll
        for (int ci = 0; ci < 3; ++ci) {
            float xr[25];
            #pragma unroll
            for (int ky = 0; ky < 5; ++ky)
                #pragma unroll
                for (int kx = 0; kx < 5; ++kx)
                    xr[ky * 5 + kx] = xs[ci][yy + ky][xx + kx];
            #pragma unroll
            for (int c = 0; c < 16; ++c) {
                const float* wr = W1 + (c * 3 + ci) * 25;   // block-uniform -> s_load
                float a = acc[c];
                #pragma unroll
                for (int k = 0; k < 25; ++k) a = fmaf(wr[k], xr[k], a);
                acc[c] = a;
            }
        }
        // 2x2 max-pool via shuffles: partners pos^1 (x) and pos^32 (y), both in-wave
        const bool win = ((pos & 1) == 0) && ((pos & 32) == 0);
        const int py = pos >> 6, px = (pos & 31) >> 1;
        float* hb = h1 + (size_t)b * 4096 + py * 16 + px;
        #pragma unroll
        for (int c = 0; c < 16; ++c) {
            float m = acc[c];
            m = fmaxf(m, __shfl_xor(m, 1));
            m = fmaxf(m, __shfl_xor(m, 32));
            if (win) hb[c * 256] = fmaxf(m, 0.f) * ((kh1[c] == qh) ? 1.f : 0.f);
        }
    }
}

// ---------------------------------------------------------------------------
// conv2: h1[B,16,16,16] f32 -> h2[B,20,8,8] f32
// thread = one pre-pool position (256 = 16x16); all 20 co in registers;
// scalar weights; shfl pooling. LDS ~26 KB -> ~5 blocks/CU.
// ---------------------------------------------------------------------------
__global__ __launch_bounds__(256) void conv2_kernel(
    const float* __restrict__ h1, const float* __restrict__ W2,
    const float* __restrict__ b2, const int* __restrict__ kh2,
    const double* __restrict__ dmeta, float* __restrict__ h2)
{
    __shared__ float xs[16][20][20];
    __shared__ double s_csum[16];

    const int b = blockIdx.x, t = threadIdx.x;

    for (int i = t; i < 6400; i += 256) (&xs[0][0][0])[i] = 0.f;
    __syncthreads();
    const float2* xb2 = (const float2*)(h1 + (size_t)b * 4096);
    for (int i = t; i < 2048; i += 256) {
        int idx = i * 2;
        int c = idx >> 8, rem = idx & 255;
        *(float2*)&xs[c][(rem >> 4) + 2][(rem & 15) + 2] = xb2[i];
    }
    __syncthreads();
    {   // channel sums: wave w reduces channels 4w..4w+3
        int w = t >> 6, ln = t & 63;
        #pragma unroll
        for (int cc = 0; cc < 4; ++cc) {
            int c = w * 4 + cc;
            double s = 0;
            #pragma unroll
            for (int j = 0; j < 4; ++j) {
                int i = ln + 64 * j;
                s += (double)xs[c][(i >> 4) + 2][(i & 15) + 2];
            }
            #pragma unroll
            for (int off = 32; off; off >>= 1) s += __shfl_xor(s, off);
            if (ln == 0) s_csum[c] = s;
        }
    }
    __syncthreads();
    double dp = 0, nn = 0;
    #pragma unroll
    for (int c = 0; c < 16; ++c) {
        double cm = s_csum[c] * (1.0 / 256.0);
        dp += cm * dmeta[3 + c]; nn += cm * cm;
    }
    const int qh = fmod2((dp / (5.0 * sqrt(nn) + EPSV) + dmeta[40]) / RHASH);

    const int yy = t >> 4, xx = t & 15;
    float acc[20];
    #pragma unroll
    for (int c = 0; c < 20; ++c) acc[c] = b2[c];
    for (int ci = 0; ci < 16; ++ci) {
        float xr[25];
        #pragma unroll
        for (int ky = 0; ky < 5; ++ky)
            #pragma unroll
            for (int kx = 0; kx < 5; ++kx)
                xr[ky * 5 + kx] = xs[ci][yy + ky][xx + kx];
        #pragma unroll
        for (int c = 0; c < 20; ++c) {
            const float* wr = W2 + (c * 16 + ci) * 25;   // block-uniform -> s_load
            float a = acc[c];
            #pragma unroll
            for (int k = 0; k < 25; ++k) a = fmaf(wr[k], xr[k], a);
            acc[c] = a;
        }
    }
    // pool: partners t^1 (x) and t^16 (y), both in-wave
    const bool win = ((t & 1) == 0) && ((t & 16) == 0);
    const int py = t >> 5, px = (t & 15) >> 1;
    float* ob = h2 + (size_t)b * 1280 + py * 8 + px;
    #pragma unroll
    for (int c = 0; c < 20; ++c) {
        float m = acc[c];
        m = fmaxf(m, __shfl_xor(m, 1));
        m = fmaxf(m, __shfl_xor(m, 16));
        if (win) ob[c * 64] = fmaxf(m, 0.f) * ((kh2[c] == qh) ? 1.f : 0.f);
    }
}

// ---------------------------------------------------------------------------
// conv3 + final linear: h2[B,20,8,8] f32 -> out[B,10] f32
// 4 samples per block; wave = one sample (64 lanes = 64 pre-pool positions);
// scalar W3; per-wave butterfly means+hash (no cross-wave sync needed);
// shfl pooling into LDS flat, then 160 threads do the 320->10 linear.
// ---------------------------------------------------------------------------
__global__ __launch_bounds__(256) void conv3_kernel(
    const float* __restrict__ h2, const float* __restrict__ W3,
    const float* __restrict__ b3, const int* __restrict__ kh3,
    const double* __restrict__ dmeta,
    const float* __restrict__ Wo, const float* __restrict__ bo,
    float* __restrict__ out, int B)
{
    __shared__ float xs[4][20][12][12];
    __shared__ float flat[4][320];

    const int b0 = blockIdx.x * 4, t = threadIdx.x;

    for (int i = t; i < 4 * 20 * 12 * 12; i += 256) (&xs[0][0][0][0])[i] = 0.f;
    __syncthreads();
    for (int i = t; i < 2560; i += 256) {           // 2560 float2 = 4 x 1280 floats
        int s = i / 640, r2 = i - s * 640;
        if (b0 + s < B) {
            int idx = r2 * 2;
            int c = idx >> 6, rem = idx & 63;
            *(float2*)&xs[s][c][(rem >> 3) + 2][(rem & 7) + 2] =
                ((const float2*)(h2 + (size_t)(b0 + s) * 1280))[r2];
        }
    }
    __syncthreads();

    const int s = t >> 6, ln = t & 63;
    const int yy = ln >> 3, xx = ln & 7;

    // per-wave channel means + hash (butterfly leaves sum in every lane)
    double dp = 0, nn = 0;
    #pragma unroll
    for (int c = 0; c < 20; ++c) {
        double sg = (double)xs[s][c][yy + 2][xx + 2];
        #pragma unroll
        for (int off = 32; off; off >>= 1) sg += __shfl_xor(sg, off);
        double cm = sg * (1.0 / 64.0);
        dp += cm * dmeta[19 + c]; nn += cm * cm;
    }
    const int qh = fmod2((dp / (5.0 * sqrt(nn) + EPSV) + dmeta[41]) / RHASH);

    float acc[20];
    #pragma unroll
    for (int c = 0; c < 20; ++c) acc[c] = b3[c];
    for (int ci = 0; ci < 20; ++ci) {
        float xr[25];
        #pragma unroll
        for (int ky = 0; ky < 5; ++ky)
            #pragma unroll
            for (int kx = 0; kx < 5; ++kx)
                xr[ky * 5 + kx] = xs[s][ci][yy + ky][xx + kx];
        #pragma unroll
        for (int c = 0; c < 20; ++c) {
            const float* wr = W3 + (c * 20 + ci) * 25;   // block-uniform -> s_load
            float a = acc[c];
            #pragma unroll
            for (int k = 0; k < 25; ++k) a = fmaf(wr[k], xr[k], a);
            acc[c] = a;
        }
    }
    // pool: partners ln^1 (x) and ln^8 (y); winners write flat[s][co*16+pp]
    const bool win = ((ln & 1) == 0) && ((ln & 8) == 0);
    const int pp = (ln >> 4) * 4 + ((ln & 7) >> 1);
    #pragma unroll
    for (int c = 0; c < 20; ++c) {
        float m = acc[c];
        m = fmaxf(m, __shfl_xor(m, 1));
        m = fmaxf(m, __shfl_xor(m, 8));
        if (win) flat[s][c * 16 + pp] = fmaxf(m, 0.f) * ((kh3[c] == qh) ? 1.f : 0.f);
    }
    __syncthreads();

    // linear 320->10 for 4 samples: 40 (s,o) pairs x 4 lanes each
    if (t < 160) {
        const int g = t >> 2, q = t & 3;
        const int ss = g / 10, o = g - ss * 10;
        float a = 0.f;
        const float* wr = Wo + o * 320;
        for (int k = q; k < 320; k += 4) a = fmaf(flat[ss][k], wr[k], a);
        a += __shfl_xor(a, 1);
        a += __shfl_xor(a, 2);
        if (q == 0 && b0 + ss < B) out[(size_t)(b0 + ss) * 10 + o] = a + bo[o];
    }
}

// ---------------------------------------------------------------------------
extern "C" void kernel_launch(void* const* d_in, const int* in_sizes, int n_in,
                              void* d_out, int out_size, void* d_ws, size_t ws_size,
                              hipStream_t stream)
{
    const float* x  = (const float*)d_in[0];
    const float* W1 = (const float*)d_in[1];
    const float* b1 = (const float*)d_in[2];
    const float* a1 = (const float*)d_in[3];
    const float* c1 = (const float*)d_in[4];
    const float* W2 = (const float*)d_in[5];
    const float* b2 = (const float*)d_in[6];
    const float* a2 = (const float*)d_in[7];
    const float* c2 = (const float*)d_in[8];
    const float* W3 = (const float*)d_in[9];
    const float* b3 = (const float*)d_in[10];
    const float* a3 = (const float*)d_in[11];
    const float* c3 = (const float*)d_in[12];
    const float* Wo = (const float*)d_in[13];
    const float* bo = (const float*)d_in[14];
    float* out = (float*)d_out;

    const int B = in_sizes[0] / 3072;   // 4096

    float* h1  = (float*)d_ws;                       // B*4096 f32
    float* h2  = h1 + (size_t)B * 4096;              // B*1280 f32
    double* dmeta = (double*)(h2 + (size_t)B * 1280);// 42 doubles (8B aligned)
    int* imeta = (int*)(dmeta + 42);                 // 56 ints

    setup_kernel<<<1, 256, 0, stream>>>(W1, a1, c1, W2, a2, c2, W3, a3, c3, dmeta, imeta);
    conv1_kernel<<<B, 256, 0, stream>>>(x, W1, b1, imeta, dmeta, h1);
    conv2_kernel<<<B, 256, 0, stream>>>(h1, W2, b2, imeta + 16, dmeta, h2);
    conv3_kernel<<<(B + 3) / 4, 256, 0, stream>>>(h2, W3, b3, imeta + 36, dmeta, Wo, bo, out, B);
}

// Round 4
// 558.343 us; speedup vs baseline: 2.1221x; 2.1221x over previous
//
#include <hip/hip_runtime.h>
#include <hip/hip_bf16.h>

#define EPSV 1e-12
#define RHASH 0.2

__device__ __forceinline__ int fmod2(double t) {
    // floor then mod 2 with numpy semantics (non-negative result)
    return (int)(((long long)floor(t)) & 1LL);
}

// ---------------------------------------------------------------------------
// setup: per-layer kernel hashes kh[], per-cin a-sums, query constants (double)
// dmeta layout: [0..2]=asum1, [3..18]=asum2, [19..38]=asum3, [39]=qc1,[40]=qc2,[41]=qc3
// imeta layout: [0..15]=kh1, [16..35]=kh2, [36..55]=kh3
// (identical to the verified round-2 version)
// ---------------------------------------------------------------------------
__device__ void layer_setup(const float* W, const float* a, double cval,
                            int Co, int Ci, int* kh, double* asum, double* qc,
                            double* s_norm, float* Wbuf, float* abuf)
{
    const int t = threadIdx.x;
    const int D = Ci * 25;
    for (int i = t; i < Co * D; i += 256) Wbuf[i] = W[i];
    for (int i = t; i < D + 5; i += 256) abuf[i] = a[i];
    __syncthreads();
    if (t < Co) {
        double s = 0;
        for (int j = 0; j < D; ++j) { double w = (double)Wbuf[t * D + j]; s += w * w; }
        s_norm[t] = sqrt(s);
    }
    __syncthreads();
    if (t == 0) {
        double mx = 0;
        for (int i = 0; i < Co; ++i) mx = fmax(mx, s_norm[i]);
        s_norm[23] = 1.0 / (mx + EPSV);
    }
    __syncthreads();
    double scale = s_norm[23];
    if (t < Co) {
        double dp = 0;
        for (int j = 0; j < D; ++j) dp += (double)Wbuf[t * D + j] * (double)abuf[j];
        dp *= scale;
        double n = s_norm[t] * scale;
        double p = n * n;                       // n^2, n^4, n^8, n^16, n^32
        for (int m = 0; m < 5; ++m) { dp += p * (double)abuf[D + m]; p *= p; }
        kh[t] = fmod2((dp + cval) / RHASH);
    }
    if (t >= 64 && t < 64 + Ci) {
        int c = t - 64;
        double s = 0;
        for (int j = 0; j < 25; ++j) s += (double)abuf[c * 25 + j];
        asum[c] = s;
    }
    if (t == 128) {
        double s = 0;
        for (int m = 0; m < 5; ++m) s += (double)abuf[D + m];
        *qc = 0.5 * s + cval;
    }
    __syncthreads();
}

__global__ __launch_bounds__(256) void setup_kernel(
    const float* W1, const float* a1, const float* c1,
    const float* W2, const float* a2, const float* c2,
    const float* W3, const float* a3, const float* c3,
    double* dmeta, int* imeta)
{
    __shared__ float Wbuf[10000];
    __shared__ float abuf[512];
    __shared__ double s_norm[24];
    layer_setup(W1, a1, (double)c1[0], 16, 3,  imeta + 0,  dmeta + 0,  dmeta + 39, s_norm, Wbuf, abuf);
    layer_setup(W2, a2, (double)c2[0], 20, 16, imeta + 16, dmeta + 3,  dmeta + 40, s_norm, Wbuf, abuf);
    layer_setup(W3, a3, (double)c3[0], 20, 20, imeta + 36, dmeta + 19, dmeta + 41, s_norm, Wbuf, abuf);
}

// ---------------------------------------------------------------------------
// weight repack:
// Wp1: [ci3][ky5][kx5][co16]                  = 1200 floats
// Wp2: [ci16][ky5][cog4][28] (j=clocal*5+kx)  = 8960 floats
// Wp3: [ci20][ky5][cog4][28]                  = 11200 floats
// ---------------------------------------------------------------------------
__global__ __launch_bounds__(256) void pack_kernel(const float* W1, const float* W2, const float* W3,
                                                   float* Wp1, float* Wp2, float* Wp3)
{
    int i = blockIdx.x * 256 + threadIdx.x;
    if (i < 1200) {
        int co = i & 15, r = i >> 4;           // r = (ci*5+ky)*5+kx
        int kx = r % 5, r2 = r / 5, ky = r2 % 5, ci = r2 / 5;
        Wp1[i] = W1[co * 75 + ci * 25 + ky * 5 + kx];
    } else if (i < 1200 + 8960) {
        int k = i - 1200;
        int j = k % 28, r = k / 28;            // r = (ci*5+ky)*4+cog
        int cog = r % 4, r2 = r / 4, ky = r2 % 5, ci = r2 / 5;
        Wp2[k] = (j < 25) ? W2[(cog * 5 + j / 5) * 400 + ci * 25 + ky * 5 + (j % 5)] : 0.f;
    } else if (i < 1200 + 8960 + 11200) {
        int k = i - 10160;
        int j = k % 28, r = k / 28;
        int cog = r % 4, r2 = r / 4, ky = r2 % 5, ci = r2 / 5;
        Wp3[k] = (j < 25) ? W3[(cog * 5 + j / 5) * 500 + ci * 25 + ky * 5 + (j % 5)] : 0.f;
    }
}

// ---------------------------------------------------------------------------
// hash kernels: one wave per sample computes qh for the next layer
// ---------------------------------------------------------------------------
__global__ __launch_bounds__(256) void hq1_kernel(const float* __restrict__ x,
    const double* __restrict__ dmeta, int* __restrict__ qh1, int B)
{
    int b = blockIdx.x * 4 + (threadIdx.x >> 6);
    int ln = threadIdx.x & 63;
    if (b >= B) return;
    const float4* xb = (const float4*)(x + (size_t)b * 3072);
    double dp = 0, nn = 0;
    for (int c = 0; c < 3; ++c) {
        double s = 0;
        #pragma unroll
        for (int j = 0; j < 4; ++j) {
            float4 v = xb[c * 256 + ln + 64 * j];
            s += (double)v.x + (double)v.y + (double)v.z + (double)v.w;
        }
        #pragma unroll
        for (int off = 32; off; off >>= 1) s += __shfl_xor(s, off);
        double cm = s * (1.0 / 1024.0);
        dp += cm * dmeta[c]; nn += cm * cm;
    }
    int qh = fmod2((dp / (5.0 * sqrt(nn) + EPSV) + dmeta[39]) / RHASH);
    if (ln == 0) qh1[b] = qh;
}

__global__ __launch_bounds__(256) void hq2_kernel(const float* __restrict__ h1,
    const double* __restrict__ dmeta, int* __restrict__ qh2, int B)
{
    int b = blockIdx.x * 4 + (threadIdx.x >> 6);
    int ln = threadIdx.x & 63;
    if (b >= B) return;
    const float4* hb = (const float4*)(h1 + (size_t)b * 4096);
    double dp = 0, nn = 0;
    for (int c = 0; c < 16; ++c) {
        float4 v = hb[c * 64 + ln];
        double s = (double)v.x + (double)v.y + (double)v.z + (double)v.w;
        #pragma unroll
        for (int off = 32; off; off >>= 1) s += __shfl_xor(s, off);
        double cm = s * (1.0 / 256.0);
        dp += cm * dmeta[3 + c]; nn += cm * cm;
    }
    int qh = fmod2((dp / (5.0 * sqrt(nn) + EPSV) + dmeta[40]) / RHASH);
    if (ln == 0) qh2[b] = qh;
}

__global__ __launch_bounds__(256) void hq3_kernel(const float* __restrict__ h2,
    const double* __restrict__ dmeta, int* __restrict__ qh3, int B)
{
    int b = blockIdx.x * 4 + (threadIdx.x >> 6);
    int ln = threadIdx.x & 63;
    if (b >= B) return;
    const float4* hb = (const float4*)(h2 + (size_t)b * 1280);   // 320 float4
    int g = ln >> 4;
    double dp = 0, nn = 0;
    #pragma unroll
    for (int j = 0; j < 5; ++j) {
        float4 v = hb[ln + 64 * j];
        double s = (double)v.x + (double)v.y + (double)v.z + (double)v.w;
        // reduce within 16-lane group (all lanes of a group hold the same channel)
        #pragma unroll
        for (int off = 1; off < 16; off <<= 1) s += __shfl_xor(s, off);
        int c = g + 4 * j;                   // channel = (ln + 64j)/16
        double cm = s * (1.0 / 64.0);
        dp += cm * dmeta[19 + c]; nn += cm * cm;
    }
    dp += __shfl_xor(dp, 16); dp += __shfl_xor(dp, 32);
    nn += __shfl_xor(nn, 16); nn += __shfl_xor(nn, 32);
    int qh = fmod2((dp / (5.0 * sqrt(nn) + EPSV) + dmeta[41]) / RHASH);
    if (ln == 0) qh3[b] = qh;
}

// ---------------------------------------------------------------------------
// conv1: x[B,3,32,32] -> h1[B,16,16,16]; block=sample; thread=pooled pos,
// all 16 co, 2x2 quad in-thread. Weights broadcast from LDS [ci][ky][kx][co16].
// LDS ~20.4KB.
// ---------------------------------------------------------------------------
__global__ __launch_bounds__(256) void conv1_kernel(
    const float* __restrict__ x, const float* __restrict__ Wp1,
    const float* __restrict__ b1, const int* __restrict__ kh1,
    const int* __restrict__ qh1, float* __restrict__ h1)
{
    __shared__ float xs[3][36][36];
    __shared__ float Ws[1200];

    const int b = blockIdx.x, t = threadIdx.x;

    for (int i = t; i < 3 * 36 * 36; i += 256) (&xs[0][0][0])[i] = 0.f;
    for (int i = t; i < 600; i += 256) ((float2*)Ws)[i] = ((const float2*)Wp1)[i];
    __syncthreads();
    const float2* xb2 = (const float2*)(x + (size_t)b * 3072);
    for (int i = t; i < 1536; i += 256) {
        int idx = i * 2, c = idx >> 10, rem = idx & 1023;
        *(float2*)&xs[c][(rem >> 5) + 2][(rem & 31) + 2] = xb2[i];
    }
    __syncthreads();

    const int qh = qh1[b];
    const int py = t >> 4, px = t & 15;
    const int y0 = 2 * py, x0 = 2 * px;

    float acc[16][4];
    #pragma unroll
    for (int c = 0; c < 16; ++c) {
        float bb = b1[c];
        acc[c][0] = bb; acc[c][1] = bb; acc[c][2] = bb; acc[c][3] = bb;
    }
    #pragma unroll
    for (int ci = 0; ci < 3; ++ci) {
        #pragma unroll
        for (int ky = 0; ky < 5; ++ky) {
            float xr0[6], xr1[6];
            {
                float2 a0 = *(const float2*)&xs[ci][y0 + ky][x0];
                float2 a1 = *(const float2*)&xs[ci][y0 + ky][x0 + 2];
                float2 a2 = *(const float2*)&xs[ci][y0 + ky][x0 + 4];
                float2 c0 = *(const float2*)&xs[ci][y0 + ky + 1][x0];
                float2 c1 = *(const float2*)&xs[ci][y0 + ky + 1][x0 + 2];
                float2 c2 = *(const float2*)&xs[ci][y0 + ky + 1][x0 + 4];
                xr0[0]=a0.x; xr0[1]=a0.y; xr0[2]=a1.x; xr0[3]=a1.y; xr0[4]=a2.x; xr0[5]=a2.y;
                xr1[0]=c0.x; xr1[1]=c0.y; xr1[2]=c1.x; xr1[3]=c1.y; xr1[4]=c2.x; xr1[5]=c2.y;
            }
            const float* wbase = Ws + ((ci * 5 + ky) * 5) * 16;
            #pragma unroll
            for (int kx = 0; kx < 5; ++kx) {
                float wc[16];
                const float4* wp = (const float4*)(wbase + kx * 16);
                *(float4*)&wc[0]  = wp[0];
                *(float4*)&wc[4]  = wp[1];
                *(float4*)&wc[8]  = wp[2];
                *(float4*)&wc[12] = wp[3];
                #pragma unroll
                for (int c = 0; c < 16; ++c) {
                    acc[c][0] = fmaf(wc[c], xr0[kx],     acc[c][0]);
                    acc[c][1] = fmaf(wc[c], xr0[kx + 1], acc[c][1]);
                    acc[c][2] = fmaf(wc[c], xr1[kx],     acc[c][2]);
                    acc[c][3] = fmaf(wc[c], xr1[kx + 1], acc[c][3]);
                }
            }
        }
    }
    float* hb = h1 + (size_t)b * 4096 + t;
    #pragma unroll
    for (int c = 0; c < 16; ++c) {
        float m = fmaxf(fmaxf(acc[c][0], acc[c][1]), fmaxf(acc[c][2], acc[c][3]));
        hb[c * 256] = fmaxf(m, 0.f) * ((kh1[c] == qh) ? 1.f : 0.f);
    }
}

// ---------------------------------------------------------------------------
// conv2: h1[B,16,16,16] -> h2[B,20,8,8]; block=sample; thread=(cog4 x pos64),
// 5 co x 2x2 quad. K chunked in 2x8 ci. Wave-uniform weight rows (broadcast).
// LDS = 12.8 + 17.9 = 30.7KB -> 5 blocks/CU.
// ---------------------------------------------------------------------------
__global__ __launch_bounds__(256) void conv2_kernel(
    const float* __restrict__ h1, const float* __restrict__ Wp2,
    const float* __restrict__ b2, const int* __restrict__ kh2,
    const int* __restrict__ qh2, float* __restrict__ h2)
{
    __shared__ float xs[8][20][20];
    __shared__ float Ws[4480];           // [ci8][ky5][cog4][28]

    const int b = blockIdx.x, t = threadIdx.x;
    const int cog = t >> 6, pos = t & 63;
    const int py = pos >> 3, px = pos & 7;
    const int y0 = 2 * py, x0 = 2 * px;

    for (int i = t; i < 8 * 20 * 20; i += 256) (&xs[0][0][0])[i] = 0.f;

    const int qh = qh2[b];
    float acc[5][4];
    #pragma unroll
    for (int c = 0; c < 5; ++c) {
        float bb = b2[cog * 5 + c];
        acc[c][0] = bb; acc[c][1] = bb; acc[c][2] = bb; acc[c][3] = bb;
    }
    __syncthreads();

    for (int ch = 0; ch < 2; ++ch) {
        for (int i = t; i < 2240; i += 256)
            ((float2*)Ws)[i] = ((const float2*)(Wp2 + ch * 4480))[i];
        const float2* src = (const float2*)(h1 + (size_t)b * 4096 + ch * 2048);
        for (int i = t; i < 1024; i += 256) {
            int ci = i >> 7, r = i & 127, p2 = r * 2;
            *(float2*)&xs[ci][(p2 >> 4) + 2][(p2 & 15) + 2] = src[i];
        }
        __syncthreads();

        for (int ci = 0; ci < 8; ++ci) {
            #pragma unroll
            for (int ky = 0; ky < 5; ++ky) {
                float xr0[6], xr1[6];
                {
                    float2 a0 = *(const float2*)&xs[ci][y0 + ky][x0];
                    float2 a1 = *(const float2*)&xs[ci][y0 + ky][x0 + 2];
                    float2 a2 = *(const float2*)&xs[ci][y0 + ky][x0 + 4];
                    float2 c0 = *(const float2*)&xs[ci][y0 + ky + 1][x0];
                    float2 c1 = *(const float2*)&xs[ci][y0 + ky + 1][x0 + 2];
                    float2 c2 = *(const float2*)&xs[ci][y0 + ky + 1][x0 + 4];
                    xr0[0]=a0.x; xr0[1]=a0.y; xr0[2]=a1.x; xr0[3]=a1.y; xr0[4]=a2.x; xr0[5]=a2.y;
                    xr1[0]=c0.x; xr1[1]=c0.y; xr1[2]=c1.x; xr1[3]=c1.y; xr1[4]=c2.x; xr1[5]=c2.y;
                }
                float wv[28];
                const float4* wp = (const float4*)&Ws[((ci * 5 + ky) * 4 + cog) * 28];
                *(float4*)&wv[0]  = wp[0];
                *(float4*)&wv[4]  = wp[1];
                *(float4*)&wv[8]  = wp[2];
                *(float4*)&wv[12] = wp[3];
                *(float4*)&wv[16] = wp[4];
                *(float4*)&wv[20] = wp[5];
                *(float4*)&wv[24] = wp[6];
                #pragma unroll
                for (int c = 0; c < 5; ++c) {
                    #pragma unroll
                    for (int kx = 0; kx < 5; ++kx) {
                        float w = wv[c * 5 + kx];
                        acc[c][0] = fmaf(w, xr0[kx],     acc[c][0]);
                        acc[c][1] = fmaf(w, xr0[kx + 1], acc[c][1]);
                        acc[c][2] = fmaf(w, xr1[kx],     acc[c][2]);
                        acc[c][3] = fmaf(w, xr1[kx + 1], acc[c][3]);
                    }
                }
            }
        }
        __syncthreads();
    }

    float* ob = h2 + (size_t)b * 1280 + pos;
    #pragma unroll
    for (int c = 0; c < 5; ++c) {
        int co = cog * 5 + c;
        float m = fmaxf(fmaxf(acc[c][0], acc[c][1]), fmaxf(acc[c][2], acc[c][3]));
        ob[co * 64] = fmaxf(m, 0.f) * ((kh2[co] == qh) ? 1.f : 0.f);
    }
}

// ---------------------------------------------------------------------------
// conv3 + linear: h2[B,20,8,8] -> out[B,10]; block = 4 samples;
// thread = (s4 x cog4 x pos16), 5 co x 2x2 quad; K chunked in 4x5 ci.
// LDS = 11.5 + 11.2 + 5.1 = 27.8KB.
// ---------------------------------------------------------------------------
__global__ __launch_bounds__(256) void conv3_kernel(
    const float* __restrict__ h2, const float* __restrict__ Wp3,
    const float* __restrict__ b3, const int* __restrict__ kh3,
    const int* __restrict__ qh3,
    const float* __restrict__ Wo, const float* __restrict__ bo,
    float* __restrict__ out, int B)
{
    __shared__ float xs[4][5][12][12];
    __shared__ float Ws[2800];           // [ci5][ky5][cog4][28]
    __shared__ float flat[4][320];

    const int b0 = blockIdx.x * 4, t = threadIdx.x;
    const int s = t >> 6, q = t & 63, cog = q >> 4, pos = q & 15;
    const int py = pos >> 2, px = pos & 3;
    const int y0 = 2 * py, x0 = 2 * px;
    const int b = b0 + s;

    for (int i = t; i < 4 * 5 * 144; i += 256) (&xs[0][0][0][0])[i] = 0.f;

    const int qh = (b < B) ? qh3[b] : 0;
    float acc[5][4];
    #pragma unroll
    for (int c = 0; c < 5; ++c) {
        float bb = b3[cog * 5 + c];
        acc[c][0] = bb; acc[c][1] = bb; acc[c][2] = bb; acc[c][3] = bb;
    }
    __syncthreads();

    for (int ch = 0; ch < 4; ++ch) {
        for (int i = t; i < 1400; i += 256)
            ((float2*)Ws)[i] = ((const float2*)(Wp3 + ch * 2800))[i];
        for (int i = t; i < 640; i += 256) {
            int ss = i / 160, r = i - ss * 160, ci = r >> 5, rr = r & 31, p2 = rr * 2;
            if (b0 + ss < B)
                *(float2*)&xs[ss][ci][(p2 >> 3) + 2][(p2 & 7) + 2] =
                    ((const float2*)(h2 + (size_t)(b0 + ss) * 1280 + (ch * 5 + ci) * 64))[rr];
        }
        __syncthreads();

        #pragma unroll
        for (int ci = 0; ci < 5; ++ci) {
            #pragma unroll
            for (int ky = 0; ky < 5; ++ky) {
                float xr0[6], xr1[6];
                {
                    float2 a0 = *(const float2*)&xs[s][ci][y0 + ky][x0];
                    float2 a1 = *(const float2*)&xs[s][ci][y0 + ky][x0 + 2];
                    float2 a2 = *(const float2*)&xs[s][ci][y0 + ky][x0 + 4];
                    float2 c0 = *(const float2*)&xs[s][ci][y0 + ky + 1][x0];
                    float2 c1 = *(const float2*)&xs[s][ci][y0 + ky + 1][x0 + 2];
                    float2 c2 = *(const float2*)&xs[s][ci][y0 + ky + 1][x0 + 4];
                    xr0[0]=a0.x; xr0[1]=a0.y; xr0[2]=a1.x; xr0[3]=a1.y; xr0[4]=a2.x; xr0[5]=a2.y;
                    xr1[0]=c0.x; xr1[1]=c0.y; xr1[2]=c1.x; xr1[3]=c1.y; xr1[4]=c2.x; xr1[5]=c2.y;
                }
                float wv[28];
                const float4* wp = (const float4*)&Ws[((ci * 5 + ky) * 4 + cog) * 28];
                *(float4*)&wv[0]  = wp[0];
                *(float4*)&wv[4]  = wp[1];
                *(float4*)&wv[8]  = wp[2];
                *(float4*)&wv[12] = wp[3];
                *(float4*)&wv[16] = wp[4];
                *(float4*)&wv[20] = wp[5];
                *(float4*)&wv[24] = wp[6];
                #pragma unroll
                for (int c = 0; c < 5; ++c) {
                    #pragma unroll
                    for (int kx = 0; kx < 5; ++kx) {
                        float w = wv[c * 5 + kx];
                        acc[c][0] = fmaf(w, xr0[kx],     acc[c][0]);
                        acc[c][1] = fmaf(w, xr0[kx + 1], acc[c][1]);
                        acc[c][2] = fmaf(w, xr1[kx],     acc[c][2]);
                        acc[c][3] = fmaf(w, xr1[kx + 1], acc[c][3]);
                    }
                }
            }
        }
        __syncthreads();
    }

    #pragma unroll
    for (int c = 0; c < 5; ++c) {
        int co = cog * 5 + c;
        float m = fmaxf(fmaxf(acc[c][0], acc[c][1]), fmaxf(acc[c][2], acc[c][3]));
        flat[s][co * 16 + pos] = fmaxf(m, 0.f) * ((kh3[co] == qh) ? 1.f : 0.f);
    }
    __syncthreads();

    // linear 320->10 for 4 samples: 40 (s,o) pairs x 4 lanes each
    if (t < 160) {
        const int g = t >> 2, qq = t & 3;
        const int ss = g / 10, o = g - ss * 10;
        float a = 0.f;
        const float* wr = Wo + o * 320;
        for (int k = qq; k < 320; k += 4) a = fmaf(flat[ss][k], wr[k], a);
        a += __shfl_xor(a, 1);
        a += __shfl_xor(a, 2);
        if (qq == 0 && b0 + ss < B) out[(size_t)(b0 + ss) * 10 + o] = a + bo[o];
    }
}

// ---------------------------------------------------------------------------
extern "C" void kernel_launch(void* const* d_in, const int* in_sizes, int n_in,
                              void* d_out, int out_size, void* d_ws, size_t ws_size,
                              hipStream_t stream)
{
    const float* x  = (const float*)d_in[0];
    const float* W1 = (const float*)d_in[1];
    const float* b1 = (const float*)d_in[2];
    const float* a1 = (const float*)d_in[3];
    const float* c1 = (const float*)d_in[4];
    const float* W2 = (const float*)d_in[5];
    const float* b2 = (const float*)d_in[6];
    const float* a2 = (const float*)d_in[7];
    const float* c2 = (const float*)d_in[8];
    const float* W3 = (const float*)d_in[9];
    const float* b3 = (const float*)d_in[10];
    const float* a3 = (const float*)d_in[11];
    const float* c3 = (const float*)d_in[12];
    const float* Wo = (const float*)d_in[13];
    const float* bo = (const float*)d_in[14];
    float* out = (float*)d_out;

    const int B = in_sizes[0] / 3072;   // 4096

    float* h1  = (float*)d_ws;                       // B*4096 f32
    float* h2  = h1 + (size_t)B * 4096;              // B*1280 f32
    float* Wp1 = h2 + (size_t)B * 1280;              // 1200
    float* Wp2 = Wp1 + 1200;                         // 8960
    float* Wp3 = Wp2 + 8960;                         // 11200
    double* dmeta = (double*)(Wp3 + 11200);          // 42 doubles (8B aligned)
    int* imeta = (int*)(dmeta + 42);                 // 56 ints
    int* qh1 = imeta + 56;                           // B ints
    int* qh2 = qh1 + B;
    int* qh3 = qh2 + B;

    setup_kernel<<<1, 256, 0, stream>>>(W1, a1, c1, W2, a2, c2, W3, a3, c3, dmeta, imeta);
    pack_kernel<<<84, 256, 0, stream>>>(W1, W2, W3, Wp1, Wp2, Wp3);
    hq1_kernel<<<(B + 3) / 4, 256, 0, stream>>>(x, dmeta, qh1, B);
    conv1_kernel<<<B, 256, 0, stream>>>(x, Wp1, b1, imeta, qh1, h1);
    hq2_kernel<<<(B + 3) / 4, 256, 0, stream>>>(h1, dmeta, qh2, B);
    conv2_kernel<<<B, 256, 0, stream>>>(h1, Wp2, b2, imeta + 16, qh2, h2);
    hq3_kernel<<<(B + 3) / 4, 256, 0, stream>>>(h2, dmeta, qh3, B);
    conv3_kernel<<<(B + 3) / 4, 256, 0, stream>>>(h2, Wp3, b3, imeta + 36, qh3, Wo, bo, out, B);
}